// Round 8
// baseline (897.888 us; speedup 1.0000x reference)
//
#include <hip/hip_runtime.h>

typedef unsigned short u16;
typedef __attribute__((ext_vector_type(4))) float f32x4;
typedef __attribute__((ext_vector_type(8))) short s16x8;
typedef __attribute__((ext_vector_type(4))) unsigned short u16x4;

#define DEV __device__ __forceinline__
#define VMW(N) asm volatile("s_waitcnt vmcnt(" #N ")" ::: "memory")
#define BARM() asm volatile("s_barrier" ::: "memory")
#define SCHEDB() __builtin_amdgcn_sched_barrier(0)

// Problem constants
constexpr int Bb = 64, Tt = 2048, Dd = 1024, Cc = 1024, Ff = 256;
constexpr int TP = Tt + 4;            // padded time (2 halo rows each side)
constexpr int M1 = Bb * Tt;           // 131072

DEV u16 f2bf(float f) {               // RNE f32 -> bf16
    union { float f; unsigned u; } v; v.f = f;
    unsigned r = v.u + 0x7fffu + ((v.u >> 16) & 1u);
    return (u16)(r >> 16);
}
DEV float bf2f(u16 h) {
    union { unsigned u; float f; } v; v.u = ((unsigned)h) << 16; return v.f;
}

// async global->LDS, 16B per lane. lds dest must be wave-uniform base;
// HW writes lane l at base + l*16.
DEV void gl_lds16(const u16* g, u16* l) {
    __builtin_amdgcn_global_load_lds(
        (const __attribute__((address_space(1))) unsigned*)(const void*)g,
        (__attribute__((address_space(3))) unsigned*)(void*)l,
        16, 0, 0);
}

// T2 swizzle helpers (16B-slot XOR within 128B row):
DEV int swz_scol(int lane) { return (((lane & 7) ^ ((lane >> 3) & 7)) << 3); }
DEV int swz_rd(int row, int e) { return e ^ ((row & 7) << 3); }

// ---------------- K-1: S f32 -> bf16 ----------------
__global__ __launch_bounds__(256) void k_s2bf(const float* __restrict__ S,
                                              u16* __restrict__ Sb) {
    size_t i = ((size_t)blockIdx.x * 256 + threadIdx.x) * 8;
    const size_t stride = (size_t)gridDim.x * 256 * 8;
    const size_t n = (size_t)M1 * Dd;
    for (; i < n; i += stride) {
        f32x4 a = *(const f32x4*)(S + i);
        f32x4 b = *(const f32x4*)(S + i + 4);
        s16x8 r;
        r[0] = (short)f2bf(a.x); r[1] = (short)f2bf(a.y);
        r[2] = (short)f2bf(a.z); r[3] = (short)f2bf(a.w);
        r[4] = (short)f2bf(b.x); r[5] = (short)f2bf(b.y);
        r[6] = (short)f2bf(b.z); r[7] = (short)f2bf(b.w);
        *(s16x8*)(Sb + i) = r;
    }
}

// ---------------- K0: l2-normalize label rows, cast bf16 ----------------
__global__ __launch_bounds__(256) void k_label_norm(const float* __restrict__ L,
                                                    u16* __restrict__ Ln) {
    int c = blockIdx.x;
    int t = threadIdx.x;
    const float* row = L + (size_t)c * Dd;
    float s = 0.f;
    for (int d = t; d < Dd; d += 256) { float v = row[d]; s += v * v; }
    for (int o = 32; o; o >>= 1) s += __shfl_down(s, o);
    __shared__ float red[4];
    if ((t & 63) == 0) red[t >> 6] = s;
    __syncthreads();
    float tot = red[0] + red[1] + red[2] + red[3];
    float r = rsqrtf(fmaxf(tot, 1e-12f));
    for (int d = t; d < Dd; d += 256) Ln[(size_t)c * Dd + d] = f2bf(row[d] * r);
}

// ---------------- K0b: transpose conv_w (K,C,F) f32 -> Wt (K,F,C) bf16 --
__global__ __launch_bounds__(256) void k_wt(const float* __restrict__ W,
                                            u16* __restrict__ Wt) {
    __shared__ float tile[64][65];
    int k = blockIdx.x; int c0 = blockIdx.y * 64; int f0 = blockIdx.z * 64;
    int tid = threadIdx.x;
    const float* Wk = W + (size_t)k * Cc * Ff;
    #pragma unroll
    for (int i = 0; i < 16; ++i) {
        int q = tid + i * 256;
        int ci = q >> 6, fj = q & 63;
        tile[ci][fj] = Wk[(size_t)(c0 + ci) * Ff + f0 + fj];
    }
    __syncthreads();
    #pragma unroll
    for (int i = 0; i < 16; ++i) {
        int q = tid + i * 256;
        int fi = q >> 6, cj = q & 63;
        Wt[((size_t)k * Ff + f0 + fi) * Cc + c0 + cj] = f2bf(tile[cj][fi]);
    }
}

// ---------------- K1: zero the halo rows of padded G ----------------
__global__ __launch_bounds__(256) void k_zpad(u16* __restrict__ Gp) {
    int b_ = blockIdx.x, tid = threadIdx.x;
    size_t base = (size_t)b_ * TP * Cc;
    for (int i = tid; i < 2 * Cc; i += 256) {
        Gp[base + i] = 0;
        Gp[base + (size_t)(TP - 2) * Cc + i] = 0;
    }
}

// ---------------- K2: G = Sb @ Ln^T  (256x256 8-phase, T4 counted) ------
// Round-6 schedule, HARDENED: all barriers are memory-clobbered asm
// (bare __builtin s_barrier is NOT a compiler fence -> gl_lds intrinsics
// could sink past counted vmcnt, voiding the ledger), plus sched_barrier(0)
// after each counted wait to pin instruction motion.
__global__ __launch_bounds__(512) void k_gemm1_8ph(const u16* __restrict__ Sb,
                                                   const u16* __restrict__ Ln,
                                                   u16* __restrict__ Gp) {
    __shared__ alignas(16) u16 As[2][256 * 64];   // 64 KiB
    __shared__ alignas(16) u16 Bs[2][256 * 64];   // 64 KiB
    int bid = blockIdx.x;
    int xcd = bid & 7, idx = bid >> 3;
    int mt = xcd * 64 + (idx >> 2);      // 512 mt
    int nt = idx & 3;                    // 4 nt
    const int m0 = mt * 256, n0 = nt * 256;
    int tid = threadIdx.x, lane = tid & 63, wid = tid >> 6;
    int wm = wid >> 2, wn = wid & 3;     // 2M x 4N
    int srow = lane >> 3, scol = swz_scol(lane);
    const int rsel = lane & 15;
    const int klo = (lane >> 4) * 8, khi = 32 + klo;
    f32x4 acc[8][4] = {};

    auto stageBfull = [&](int kt, int buf) {   // 4 gl_lds/thread
        #pragma unroll
        for (int i = 0; i < 4; ++i) {
            int seg = wid * 4 + i;             // 0..31
            gl_lds16(Ln + (size_t)(n0 + seg * 8 + srow) * Dd + kt * 64 + scol,
                     &Bs[buf][seg * 512]);
        }
    };
    auto stageAh = [&](int kt, int h, int buf) {  // 2 gl_lds/thread
        #pragma unroll
        for (int i = 0; i < 2; ++i) {
            int seg = h * 16 + wid * 2 + i;
            gl_lds16(Sb + (size_t)(m0 + seg * 8 + srow) * Dd + kt * 64 + scol,
                     &As[buf][seg * 512]);
        }
    };

    // prologue: G1(0)=Bfull+Ah0 (6), then G2(0)=Ah1 (2); wait G1 only.
    stageBfull(0, 0); stageAh(0, 0, 0);
    stageAh(0, 1, 0);
    VMW(2); SCHEDB(); BARM();

    for (int kt = 0; kt < 16; ++kt) {
        const int cur = kt & 1, nxt = cur ^ 1;
        const u16* Ab = As[cur];
        const u16* Bq = Bs[cur];
        s16x8 a[4], b[4];
        // ---------- P1: A-h0, klo ----------
        #pragma unroll
        for (int f = 0; f < 4; ++f) {
            int row = wm * 64 + f * 16 + rsel;
            a[f] = *(const s16x8*)&Ab[row * 64 + swz_rd(row, klo)];
        }
        #pragma unroll
        for (int f = 0; f < 4; ++f) {
            int row = wn * 64 + f * 16 + rsel;
            b[f] = *(const s16x8*)&Bq[row * 64 + swz_rd(row, klo)];
        }
        if (kt < 15) { stageBfull(kt + 1, nxt); stageAh(kt + 1, 0, nxt); }
        BARM();
        __builtin_amdgcn_s_setprio(1);
        #pragma unroll
        for (int fm = 0; fm < 4; ++fm)
            #pragma unroll
            for (int fn = 0; fn < 4; ++fn)
                acc[fm][fn] = __builtin_amdgcn_mfma_f32_16x16x32_bf16(
                    a[fm], b[fn], acc[fm][fn], 0, 0, 0);
        __builtin_amdgcn_s_setprio(0);
        if (kt < 15) { VMW(6); } else { VMW(0); }   // A-h1(kt) landed
        SCHEDB();
        BARM();
        // ---------- P2: A-h1, klo ----------
        #pragma unroll
        for (int f = 0; f < 4; ++f) {
            int row = 128 + wm * 64 + f * 16 + rsel;
            a[f] = *(const s16x8*)&Ab[row * 64 + swz_rd(row, klo)];
        }
        if (kt < 15) stageAh(kt + 1, 1, nxt);
        BARM();
        __builtin_amdgcn_s_setprio(1);
        #pragma unroll
        for (int fm = 0; fm < 4; ++fm)
            #pragma unroll
            for (int fn = 0; fn < 4; ++fn)
                acc[4 + fm][fn] = __builtin_amdgcn_mfma_f32_16x16x32_bf16(
                    a[fm], b[fn], acc[4 + fm][fn], 0, 0, 0);
        __builtin_amdgcn_s_setprio(0);
        BARM();
        // ---------- P3: A-h0, khi ----------
        #pragma unroll
        for (int f = 0; f < 4; ++f) {
            int row = wm * 64 + f * 16 + rsel;
            a[f] = *(const s16x8*)&Ab[row * 64 + swz_rd(row, khi)];
        }
        #pragma unroll
        for (int f = 0; f < 4; ++f) {
            int row = wn * 64 + f * 16 + rsel;
            b[f] = *(const s16x8*)&Bq[row * 64 + swz_rd(row, khi)];
        }
        BARM();
        __builtin_amdgcn_s_setprio(1);
        #pragma unroll
        for (int fm = 0; fm < 4; ++fm)
            #pragma unroll
            for (int fn = 0; fn < 4; ++fn)
                acc[fm][fn] = __builtin_amdgcn_mfma_f32_16x16x32_bf16(
                    a[fm], b[fn], acc[fm][fn], 0, 0, 0);
        __builtin_amdgcn_s_setprio(0);
        BARM();
        // ---------- P4: A-h1, khi ----------
        #pragma unroll
        for (int f = 0; f < 4; ++f) {
            int row = 128 + wm * 64 + f * 16 + rsel;
            a[f] = *(const s16x8*)&Ab[row * 64 + swz_rd(row, khi)];
        }
        BARM();
        __builtin_amdgcn_s_setprio(1);
        #pragma unroll
        for (int fm = 0; fm < 4; ++fm)
            #pragma unroll
            for (int fn = 0; fn < 4; ++fn)
                acc[4 + fm][fn] = __builtin_amdgcn_mfma_f32_16x16x32_bf16(
                    a[fm], b[fn], acc[4 + fm][fn], 0, 0, 0);
        __builtin_amdgcn_s_setprio(0);
        // kt boundary: G1(kt+1) landed; G2(kt+1)=A-h1 stays in flight.
        VMW(2); SCHEDB(); BARM();
    }
    // epilogue: m<4 -> h0 rows, m>=4 -> h1 rows
    #pragma unroll
    for (int m = 0; m < 8; ++m) {
        #pragma unroll
        for (int r = 0; r < 4; ++r) {
            int row = m0 + (m >> 2) * 128 + wm * 64 + (m & 3) * 16 + (lane >> 4) * 4 + r;
            int b_ = row >> 11, t = row & 2047;
            size_t base = ((size_t)b_ * TP + t + 2) * Cc;
            #pragma unroll
            for (int n = 0; n < 4; ++n) {
                int col = n0 + wn * 64 + n * 16 + rsel;
                Gp[base + col] = f2bf(acc[m][n][r]);
            }
        }
    }
}

// ---------------- K2-fallback: f32 A path (linear LDS, consistent) ------
__global__ __launch_bounds__(256) void k_gemm1_f32(const float* __restrict__ S,
                                                   const u16* __restrict__ Ln,
                                                   u16* __restrict__ Gp) {
    __shared__ alignas(16) u16 As[128 * 64];
    __shared__ alignas(16) u16 Bs[128 * 64];
    int bid = blockIdx.x;
    int xcd = bid & 7, idx = bid >> 3;
    int mt = xcd * 128 + (idx >> 3);
    int nt = idx & 7;
    const int m0 = mt * 128, n0 = nt * 128;
    int tid = threadIdx.x;
    int lane = tid & 63, wid = tid >> 6;
    int wm = wid >> 1, wn = wid & 1;
    f32x4 acc[4][4] = {};

    for (int kt = 0; kt < 16; ++kt) {
        int k0 = kt * 64;
        #pragma unroll
        for (int i = 0; i < 8; ++i) {
            int q = tid + i * 256;
            int row = q >> 4, c4 = (q & 15) * 4;
            f32x4 v = *(const f32x4*)(S + (size_t)(m0 + row) * Dd + k0 + c4);
            u16* p = &As[row * 64 + c4];
            p[0] = f2bf(v.x); p[1] = f2bf(v.y); p[2] = f2bf(v.z); p[3] = f2bf(v.w);
        }
        #pragma unroll
        for (int i = 0; i < 4; ++i) {
            int q = tid + i * 256;
            int row = q >> 3, c8 = (q & 7) * 8;
            *(s16x8*)&Bs[row * 64 + c8] =
                *(const s16x8*)(Ln + (size_t)(n0 + row) * Dd + k0 + c8);
        }
        __syncthreads();
        #pragma unroll
        for (int kk = 0; kk < 2; ++kk) {
            int rsel = lane & 15, ksel = kk * 32 + (lane >> 4) * 8;
            s16x8 a[4], b[4];
            #pragma unroll
            for (int f = 0; f < 4; ++f)
                a[f] = *(const s16x8*)&As[(wm * 64 + f * 16 + rsel) * 64 + ksel];
            #pragma unroll
            for (int f = 0; f < 4; ++f)
                b[f] = *(const s16x8*)&Bs[(wn * 64 + f * 16 + rsel) * 64 + ksel];
            #pragma unroll
            for (int fm = 0; fm < 4; ++fm)
                #pragma unroll
                for (int fn = 0; fn < 4; ++fn)
                    acc[fm][fn] = __builtin_amdgcn_mfma_f32_16x16x32_bf16(
                        a[fm], b[fn], acc[fm][fn], 0, 0, 0);
        }
        __syncthreads();
    }
    #pragma unroll
    for (int fm = 0; fm < 4; ++fm) {
        #pragma unroll
        for (int r = 0; r < 4; ++r) {
            int row = m0 + wm * 64 + fm * 16 + (lane >> 4) * 4 + r;
            int b_ = row >> 11, t = row & 2047;
            size_t base = ((size_t)b_ * TP + t + 2) * Cc;
            #pragma unroll
            for (int fn = 0; fn < 4; ++fn) {
                int col = n0 + wn * 64 + fn * 16 + (lane & 15);
                Gp[base + col] = f2bf(acc[fm][fn][r]);
            }
        }
    }
}

// ---------------- K3: conv1d(K=5) GEMM + relu + max_f (ROUND-6 EXACT) ---
// BM=128, BN=256, 8 waves (2Mx4N). T4 counted-vmcnt, proven @378us.
__global__ __launch_bounds__(512) void k_conv(const u16* __restrict__ Gp,
                                              const u16* __restrict__ Wt,
                                              const float* __restrict__ bias,
                                              float* __restrict__ att) {
    __shared__ alignas(16) u16 As[2][24 * 512];   // 49,152 B (segs 17..23 pad)
    __shared__ alignas(16) u16 Bs[2][256 * 64];   // 65,536 B
    __shared__ float red[4][128];
    int mt = blockIdx.x;
    int b_ = mt >> 4;
    int t0 = (mt & 15) * 128;
    int tid = threadIdx.x, lane = tid & 63, wid = tid >> 6;
    int wm = wid >> 2, wn = wid & 3;
    int srow = lane >> 3, scol = swz_scol(lane);
    f32x4 acc[4][4] = {};
    const size_t gbase = ((size_t)b_ * TP + t0) * Cc;

    auto stage_B = [&](int s2) {          // 4 gl_lds/thread
        int ct2 = s2 / 5, k2 = s2 % 5, buf = s2 & 1;
        #pragma unroll
        for (int i = 0; i < 4; ++i) {
            int seg = wid * 4 + i;
            gl_lds16(Wt + ((size_t)k2 * Ff + seg * 8 + srow) * Cc + ct2 * 64 + scol,
                     &Bs[buf][seg * 512]);
        }
    };
    auto stage_A = [&](int ct2) {         // 3 gl_lds/thread (uniform, padded)
        int buf = ct2 & 1;
        #pragma unroll
        for (int i = 0; i < 3; ++i) {
            int seg = wid * 3 + i;        // 0..23; segs 17..23 load garbage
            gl_lds16(Gp + gbase + (size_t)(seg * 8 + srow) * Cc + ct2 * 64 + scol,
                     &As[buf][seg * 512]);
        }
    };
    auto compute = [&](int cb, int ca, int k) {
        #pragma unroll
        for (int kk = 0; kk < 2; ++kk) {
            int rsel = lane & 15, ksel = kk * 32 + (lane >> 4) * 8;
            s16x8 a[4], b[4];
            #pragma unroll
            for (int f = 0; f < 4; ++f) {
                int row = k + wm * 64 + f * 16 + rsel;
                a[f] = *(const s16x8*)&As[ca][row * 64 + swz_rd(row, ksel)];
            }
            #pragma unroll
            for (int f = 0; f < 4; ++f) {
                int row = wn * 64 + f * 16 + rsel;
                b[f] = *(const s16x8*)&Bs[cb][row * 64 + swz_rd(row, ksel)];
            }
            #pragma unroll
            for (int fm = 0; fm < 4; ++fm)
                #pragma unroll
                for (int fn = 0; fn < 4; ++fn)
                    acc[fm][fn] = __builtin_amdgcn_mfma_f32_16x16x32_bf16(
                        a[fm], b[fn], acc[fm][fn], 0, 0, 0);
        }
    };

    // prologue: A(0)[3] + B(0)[4] + B(1)[4] = 11 in flight
    stage_A(0); stage_B(0); stage_B(1);

    for (int ct = 0; ct < 15; ++ct) {
        int s = ct * 5, ca = ct & 1;
        // k=0
        VMW(4); BARM();
        compute(s & 1, ca, 0);
        BARM();
        stage_B(s + 2); stage_A(ct + 1);
        // k=1
        VMW(7); BARM();
        compute((s + 1) & 1, ca, 1);
        BARM();
        stage_B(s + 3);
        // k=2
        VMW(4); BARM();
        compute((s + 2) & 1, ca, 2);
        BARM();
        stage_B(s + 4);
        // k=3
        VMW(4); BARM();
        compute((s + 3) & 1, ca, 3);
        BARM();
        stage_B(s + 5);
        // k=4
        VMW(4); BARM();
        compute((s + 4) & 1, ca, 4);
        BARM();
        stage_B(s + 6);
    }
    // ct = 15 (s = 75..79): no A issue at k==0, drain tail
    VMW(4); BARM(); compute(1, 1, 0); BARM(); stage_B(77);
    VMW(4); BARM(); compute(0, 1, 1); BARM(); stage_B(78);
    VMW(4); BARM(); compute(1, 1, 2); BARM(); stage_B(79);
    VMW(4); BARM(); compute(0, 1, 3); BARM();
    VMW(0); BARM(); compute(1, 1, 4); BARM();

    // epilogue: relu(acc+bias), max over all 256 filters -> att_v
    float bv[4];
    #pragma unroll
    for (int fn = 0; fn < 4; ++fn)
        bv[fn] = bias[wn * 64 + fn * 16 + (lane & 15)];
    #pragma unroll
    for (int fm = 0; fm < 4; ++fm) {
        #pragma unroll
        for (int r = 0; r < 4; ++r) {
            float v = 0.f;
            #pragma unroll
            for (int fn = 0; fn < 4; ++fn)
                v = fmaxf(v, fmaxf(acc[fm][fn][r] + bv[fn], 0.f));
            #pragma unroll
            for (int m = 1; m <= 8; m <<= 1) v = fmaxf(v, __shfl_xor(v, m));
            if ((lane & 15) == 0)
                red[wn][wm * 64 + fm * 16 + (lane >> 4) * 4 + r] = v;
        }
    }
    __syncthreads();
    if (tid < 128) {
        float v = fmaxf(fmaxf(red[0][tid], red[1][tid]),
                        fmaxf(red[2][tid], red[3][tid]));
        att[(size_t)mt * 128 + tid] = v;
    }
}

// ---------------- K4: H partials (bf16 S) ----------------
__global__ __launch_bounds__(256) void k_henc_bf(const u16* __restrict__ Sb,
                                                 const float* __restrict__ att,
                                                 float* __restrict__ part) {
    int b_ = blockIdx.x, tc = blockIdx.y;
    int tid = threadIdx.x;
    int d = tid * 4;
    const u16* Sp = Sb + ((size_t)b_ * Tt + (size_t)tc * 256) * Dd + d;
    const float* ap = att + (size_t)b_ * Tt + (size_t)tc * 256;
    f32x4 acc = {};
    for (int t = 0; t < 256; ++t) {
        float a = ap[t];
        u16x4 s = *(const u16x4*)(Sp + (size_t)t * Dd);
        acc.x += bf2f(s.x) * a;
        acc.y += bf2f(s.y) * a;
        acc.z += bf2f(s.z) * a;
        acc.w += bf2f(s.w) * a;
    }
    *(f32x4*)(part + ((size_t)tc * Bb + b_) * Dd + d) = acc;
}

// ---------------- K4-fallback: f32 S ----------------
__global__ __launch_bounds__(256) void k_henc_f32(const float* __restrict__ S,
                                                  const float* __restrict__ att,
                                                  float* __restrict__ part) {
    int b_ = blockIdx.x, tc = blockIdx.y;
    int tid = threadIdx.x;
    int d = tid * 4;
    const float* Sp = S + ((size_t)b_ * Tt + (size_t)tc * 256) * Dd + d;
    const float* ap = att + (size_t)b_ * Tt + (size_t)tc * 256;
    f32x4 acc = {};
    for (int t = 0; t < 256; ++t) {
        float a = ap[t];
        f32x4 s = *(const f32x4*)(Sp + (size_t)t * Dd);
        acc += s * a;
    }
    *(f32x4*)(part + ((size_t)tc * Bb + b_) * Dd + d) = acc;
}

// ---------------- K5: reduce 8 partials -> d_out ----------------
__global__ __launch_bounds__(256) void k_hred(const float* __restrict__ part,
                                              float* __restrict__ out) {
    int i = blockIdx.x * 256 + threadIdx.x;
    float s = 0.f;
    #pragma unroll
    for (int p = 0; p < 8; ++p) s += part[(size_t)p * (Bb * Dd) + i];
    out[i] = s;
}

extern "C" void kernel_launch(void* const* d_in, const int* in_sizes, int n_in,
                              void* d_out, int out_size, void* d_ws, size_t ws_size,
                              hipStream_t stream) {
    const float* S  = (const float*)d_in[0];
    const float* L  = (const float*)d_in[1];
    const float* W  = (const float*)d_in[2];
    const float* cb = (const float*)d_in[3];
    float* out = (float*)d_out;
    char* ws = (char*)d_ws;

    const size_t GP_B   = (size_t)Bb * TP * Cc * 2;   // 268,959,744
    const size_t LN_B   = (size_t)Cc * Dd * 2;        //   2,097,152
    const size_t WT_B   = (size_t)5 * Ff * Cc * 2;    //   2,621,440
    const size_t ATT_B  = (size_t)M1 * 4;             //     524,288
    const size_t PART_B = (size_t)8 * Bb * Dd * 4;    //   2,097,152
    const size_t SB_B   = (size_t)M1 * Dd * 2;        // 268,435,456
    u16*   Gp   = (u16*)(ws);
    u16*   Ln   = (u16*)(ws + GP_B);
    u16*   Wt   = (u16*)(ws + GP_B + LN_B);
    float* att  = (float*)(ws + GP_B + LN_B + WT_B);
    float* part = (float*)(ws + GP_B + LN_B + WT_B + ATT_B);
    u16*   Sb   = (u16*)(ws + GP_B + LN_B + WT_B + ATT_B + PART_B);
    const bool use_bf = ws_size >= GP_B + LN_B + WT_B + ATT_B + PART_B + SB_B;

    k_label_norm<<<Cc, 256, 0, stream>>>(L, Ln);
    k_wt<<<dim3(5, Cc / 64, Ff / 64), 256, 0, stream>>>(W, Wt);
    k_zpad<<<Bb, 256, 0, stream>>>(Gp);
    if (use_bf) {
        k_s2bf<<<2048, 256, 0, stream>>>(S, Sb);
        k_gemm1_8ph<<<(M1 / 256) * (Cc / 256), 512, 0, stream>>>(Sb, Ln, Gp);
    } else {
        k_gemm1_f32<<<(M1 / 128) * (Cc / 128), 256, 0, stream>>>(S, Ln, Gp);
    }
    k_conv<<<M1 / 128, 512, 0, stream>>>(Gp, Wt, cb, att);
    if (use_bf) k_henc_bf<<<dim3(Bb, 8), 256, 0, stream>>>(Sb, att, part);
    else        k_henc_f32<<<dim3(Bb, 8), 256, 0, stream>>>(S, att, part);
    k_hred<<<(Bb * Dd) / 256, 256, 0, stream>>>(part, out);
}

// Round 10
// 829.101 us; speedup vs baseline: 1.0830x; 1.0830x over previous
//
#include <hip/hip_runtime.h>

typedef unsigned short u16;
typedef __attribute__((ext_vector_type(4))) float f32x4;
typedef __attribute__((ext_vector_type(8))) short s16x8;
typedef __attribute__((ext_vector_type(4))) unsigned short u16x4;

#define DEV __device__ __forceinline__
#define VMW(N) asm volatile("s_waitcnt vmcnt(" #N ")" ::: "memory")
#define BARM() asm volatile("s_barrier" ::: "memory")
#define SCHEDB() __builtin_amdgcn_sched_barrier(0)

// Problem constants
constexpr int Bb = 64, Tt = 2048, Dd = 1024, Cc = 1024, Ff = 256;
constexpr int TP = Tt + 4;            // padded time (2 halo rows each side)
constexpr int M1 = Bb * Tt;           // 131072

DEV u16 f2bf(float f) {               // RNE f32 -> bf16
    union { float f; unsigned u; } v; v.f = f;
    unsigned r = v.u + 0x7fffu + ((v.u >> 16) & 1u);
    return (u16)(r >> 16);
}
DEV float bf2f(u16 h) {
    union { unsigned u; float f; } v; v.u = ((unsigned)h) << 16; return v.f;
}

// async global->LDS, 16B per lane. lds dest must be wave-uniform base;
// HW writes lane l at base + l*16.
DEV void gl_lds16(const u16* g, u16* l) {
    __builtin_amdgcn_global_load_lds(
        (const __attribute__((address_space(1))) unsigned*)(const void*)g,
        (__attribute__((address_space(3))) unsigned*)(void*)l,
        16, 0, 0);
}

// T2 swizzle helpers (16B-slot XOR within 128B row):
DEV int swz_scol(int lane) { return (((lane & 7) ^ ((lane >> 3) & 7)) << 3); }
DEV int swz_rd(int row, int e) { return e ^ ((row & 7) << 3); }

// ---------------- K-1: S f32 -> bf16 ----------------
__global__ __launch_bounds__(256) void k_s2bf(const float* __restrict__ S,
                                              u16* __restrict__ Sb) {
    size_t i = ((size_t)blockIdx.x * 256 + threadIdx.x) * 8;
    const size_t stride = (size_t)gridDim.x * 256 * 8;
    const size_t n = (size_t)M1 * Dd;
    for (; i < n; i += stride) {
        f32x4 a = *(const f32x4*)(S + i);
        f32x4 b = *(const f32x4*)(S + i + 4);
        s16x8 r;
        r[0] = (short)f2bf(a.x); r[1] = (short)f2bf(a.y);
        r[2] = (short)f2bf(a.z); r[3] = (short)f2bf(a.w);
        r[4] = (short)f2bf(b.x); r[5] = (short)f2bf(b.y);
        r[6] = (short)f2bf(b.z); r[7] = (short)f2bf(b.w);
        *(s16x8*)(Sb + i) = r;
    }
}

// ---------------- K0: l2-normalize label rows, cast bf16 ----------------
__global__ __launch_bounds__(256) void k_label_norm(const float* __restrict__ L,
                                                    u16* __restrict__ Ln) {
    int c = blockIdx.x;
    int t = threadIdx.x;
    const float* row = L + (size_t)c * Dd;
    float s = 0.f;
    for (int d = t; d < Dd; d += 256) { float v = row[d]; s += v * v; }
    for (int o = 32; o; o >>= 1) s += __shfl_down(s, o);
    __shared__ float red[4];
    if ((t & 63) == 0) red[t >> 6] = s;
    __syncthreads();
    float tot = red[0] + red[1] + red[2] + red[3];
    float r = rsqrtf(fmaxf(tot, 1e-12f));
    for (int d = t; d < Dd; d += 256) Ln[(size_t)c * Dd + d] = f2bf(row[d] * r);
}

// ---------------- K0b: transpose conv_w (K,C,F) f32 -> Wt (K,F,C) bf16 --
__global__ __launch_bounds__(256) void k_wt(const float* __restrict__ W,
                                            u16* __restrict__ Wt) {
    __shared__ float tile[64][65];
    int k = blockIdx.x; int c0 = blockIdx.y * 64; int f0 = blockIdx.z * 64;
    int tid = threadIdx.x;
    const float* Wk = W + (size_t)k * Cc * Ff;
    #pragma unroll
    for (int i = 0; i < 16; ++i) {
        int q = tid + i * 256;
        int ci = q >> 6, fj = q & 63;
        tile[ci][fj] = Wk[(size_t)(c0 + ci) * Ff + f0 + fj];
    }
    __syncthreads();
    #pragma unroll
    for (int i = 0; i < 16; ++i) {
        int q = tid + i * 256;
        int fi = q >> 6, cj = q & 63;
        Wt[((size_t)k * Ff + f0 + fi) * Cc + c0 + cj] = f2bf(tile[cj][fi]);
    }
}

// ---------------- K1: zero the halo rows of padded G ----------------
__global__ __launch_bounds__(256) void k_zpad(u16* __restrict__ Gp) {
    int b_ = blockIdx.x, tid = threadIdx.x;
    size_t base = (size_t)b_ * TP * Cc;
    for (int i = tid; i < 2 * Cc; i += 256) {
        Gp[base + i] = 0;
        Gp[base + (size_t)(TP - 2) * Cc + i] = 0;
    }
}

// ---------------- K2: G = Sb @ Ln^T  (256x256 8-phase, T4, HARDENED) ----
// Round-8 exact (passed @ absmax 8.0).
__global__ __launch_bounds__(512) void k_gemm1_8ph(const u16* __restrict__ Sb,
                                                   const u16* __restrict__ Ln,
                                                   u16* __restrict__ Gp) {
    __shared__ alignas(16) u16 As[2][256 * 64];   // 64 KiB
    __shared__ alignas(16) u16 Bs[2][256 * 64];   // 64 KiB
    int bid = blockIdx.x;
    int xcd = bid & 7, idx = bid >> 3;
    int mt = xcd * 64 + (idx >> 2);      // 512 mt
    int nt = idx & 3;                    // 4 nt
    const int m0 = mt * 256, n0 = nt * 256;
    int tid = threadIdx.x, lane = tid & 63, wid = tid >> 6;
    int wm = wid >> 2, wn = wid & 3;     // 2M x 4N
    int srow = lane >> 3, scol = swz_scol(lane);
    const int rsel = lane & 15;
    const int klo = (lane >> 4) * 8, khi = 32 + klo;
    f32x4 acc[8][4] = {};

    auto stageBfull = [&](int kt, int buf) {   // 4 gl_lds/thread
        #pragma unroll
        for (int i = 0; i < 4; ++i) {
            int seg = wid * 4 + i;             // 0..31
            gl_lds16(Ln + (size_t)(n0 + seg * 8 + srow) * Dd + kt * 64 + scol,
                     &Bs[buf][seg * 512]);
        }
    };
    auto stageAh = [&](int kt, int h, int buf) {  // 2 gl_lds/thread
        #pragma unroll
        for (int i = 0; i < 2; ++i) {
            int seg = h * 16 + wid * 2 + i;
            gl_lds16(Sb + (size_t)(m0 + seg * 8 + srow) * Dd + kt * 64 + scol,
                     &As[buf][seg * 512]);
        }
    };

    // prologue: G1(0)=Bfull+Ah0 (6), then G2(0)=Ah1 (2); wait G1 only.
    stageBfull(0, 0); stageAh(0, 0, 0);
    stageAh(0, 1, 0);
    VMW(2); SCHEDB(); BARM();

    for (int kt = 0; kt < 16; ++kt) {
        const int cur = kt & 1, nxt = cur ^ 1;
        const u16* Ab = As[cur];
        const u16* Bq = Bs[cur];
        s16x8 a[4], b[4];
        // ---------- P1: A-h0, klo ----------
        #pragma unroll
        for (int f = 0; f < 4; ++f) {
            int row = wm * 64 + f * 16 + rsel;
            a[f] = *(const s16x8*)&Ab[row * 64 + swz_rd(row, klo)];
        }
        #pragma unroll
        for (int f = 0; f < 4; ++f) {
            int row = wn * 64 + f * 16 + rsel;
            b[f] = *(const s16x8*)&Bq[row * 64 + swz_rd(row, klo)];
        }
        if (kt < 15) { stageBfull(kt + 1, nxt); stageAh(kt + 1, 0, nxt); }
        BARM();
        __builtin_amdgcn_s_setprio(1);
        #pragma unroll
        for (int fm = 0; fm < 4; ++fm)
            #pragma unroll
            for (int fn = 0; fn < 4; ++fn)
                acc[fm][fn] = __builtin_amdgcn_mfma_f32_16x16x32_bf16(
                    a[fm], b[fn], acc[fm][fn], 0, 0, 0);
        __builtin_amdgcn_s_setprio(0);
        if (kt < 15) { VMW(6); } else { VMW(0); }   // A-h1(kt) landed
        SCHEDB();
        BARM();
        // ---------- P2: A-h1, klo ----------
        #pragma unroll
        for (int f = 0; f < 4; ++f) {
            int row = 128 + wm * 64 + f * 16 + rsel;
            a[f] = *(const s16x8*)&Ab[row * 64 + swz_rd(row, klo)];
        }
        if (kt < 15) stageAh(kt + 1, 1, nxt);
        BARM();
        __builtin_amdgcn_s_setprio(1);
        #pragma unroll
        for (int fm = 0; fm < 4; ++fm)
            #pragma unroll
            for (int fn = 0; fn < 4; ++fn)
                acc[4 + fm][fn] = __builtin_amdgcn_mfma_f32_16x16x32_bf16(
                    a[fm], b[fn], acc[4 + fm][fn], 0, 0, 0);
        __builtin_amdgcn_s_setprio(0);
        BARM();
        // ---------- P3: A-h0, khi ----------
        #pragma unroll
        for (int f = 0; f < 4; ++f) {
            int row = wm * 64 + f * 16 + rsel;
            a[f] = *(const s16x8*)&Ab[row * 64 + swz_rd(row, khi)];
        }
        #pragma unroll
        for (int f = 0; f < 4; ++f) {
            int row = wn * 64 + f * 16 + rsel;
            b[f] = *(const s16x8*)&Bq[row * 64 + swz_rd(row, khi)];
        }
        BARM();
        __builtin_amdgcn_s_setprio(1);
        #pragma unroll
        for (int fm = 0; fm < 4; ++fm)
            #pragma unroll
            for (int fn = 0; fn < 4; ++fn)
                acc[fm][fn] = __builtin_amdgcn_mfma_f32_16x16x32_bf16(
                    a[fm], b[fn], acc[fm][fn], 0, 0, 0);
        __builtin_amdgcn_s_setprio(0);
        BARM();
        // ---------- P4: A-h1, khi ----------
        #pragma unroll
        for (int f = 0; f < 4; ++f) {
            int row = 128 + wm * 64 + f * 16 + rsel;
            a[f] = *(const s16x8*)&Ab[row * 64 + swz_rd(row, khi)];
        }
        BARM();
        __builtin_amdgcn_s_setprio(1);
        #pragma unroll
        for (int fm = 0; fm < 4; ++fm)
            #pragma unroll
            for (int fn = 0; fn < 4; ++fn)
                acc[4 + fm][fn] = __builtin_amdgcn_mfma_f32_16x16x32_bf16(
                    a[fm], b[fn], acc[4 + fm][fn], 0, 0, 0);
        __builtin_amdgcn_s_setprio(0);
        // kt boundary: G1(kt+1) landed; G2(kt+1)=A-h1 stays in flight.
        VMW(2); SCHEDB(); BARM();
    }
    // epilogue: m<4 -> h0 rows, m>=4 -> h1 rows
    #pragma unroll
    for (int m = 0; m < 8; ++m) {
        #pragma unroll
        for (int r = 0; r < 4; ++r) {
            int row = m0 + (m >> 2) * 128 + wm * 64 + (m & 3) * 16 + (lane >> 4) * 4 + r;
            int b_ = row >> 11, t = row & 2047;
            size_t base = ((size_t)b_ * TP + t + 2) * Cc;
            #pragma unroll
            for (int n = 0; n < 4; ++n) {
                int col = n0 + wn * 64 + n * 16 + rsel;
                Gp[base + col] = f2bf(acc[m][n][r]);
            }
        }
    }
}

// ---------------- K2-fallback: f32 A path (linear LDS, consistent) ------
__global__ __launch_bounds__(256) void k_gemm1_f32(const float* __restrict__ S,
                                                   const u16* __restrict__ Ln,
                                                   u16* __restrict__ Gp) {
    __shared__ alignas(16) u16 As[128 * 64];
    __shared__ alignas(16) u16 Bs[128 * 64];
    int bid = blockIdx.x;
    int xcd = bid & 7, idx = bid >> 3;
    int mt = xcd * 128 + (idx >> 3);
    int nt = idx & 7;
    const int m0 = mt * 128, n0 = nt * 128;
    int tid = threadIdx.x;
    int lane = tid & 63, wid = tid >> 6;
    int wm = wid >> 1, wn = wid & 1;
    f32x4 acc[4][4] = {};

    for (int kt = 0; kt < 16; ++kt) {
        int k0 = kt * 64;
        #pragma unroll
        for (int i = 0; i < 8; ++i) {
            int q = tid + i * 256;
            int row = q >> 4, c4 = (q & 15) * 4;
            f32x4 v = *(const f32x4*)(S + (size_t)(m0 + row) * Dd + k0 + c4);
            u16* p = &As[row * 64 + c4];
            p[0] = f2bf(v.x); p[1] = f2bf(v.y); p[2] = f2bf(v.z); p[3] = f2bf(v.w);
        }
        #pragma unroll
        for (int i = 0; i < 4; ++i) {
            int q = tid + i * 256;
            int row = q >> 3, c8 = (q & 7) * 8;
            *(s16x8*)&Bs[row * 64 + c8] =
                *(const s16x8*)(Ln + (size_t)(n0 + row) * Dd + k0 + c8);
        }
        __syncthreads();
        #pragma unroll
        for (int kk = 0; kk < 2; ++kk) {
            int rsel = lane & 15, ksel = kk * 32 + (lane >> 4) * 8;
            s16x8 a[4], b[4];
            #pragma unroll
            for (int f = 0; f < 4; ++f)
                a[f] = *(const s16x8*)&As[(wm * 64 + f * 16 + rsel) * 64 + ksel];
            #pragma unroll
            for (int f = 0; f < 4; ++f)
                b[f] = *(const s16x8*)&Bs[(wn * 64 + f * 16 + rsel) * 64 + ksel];
            #pragma unroll
            for (int fm = 0; fm < 4; ++fm)
                #pragma unroll
                for (int fn = 0; fn < 4; ++fn)
                    acc[fm][fn] = __builtin_amdgcn_mfma_f32_16x16x32_bf16(
                        a[fm], b[fn], acc[fm][fn], 0, 0, 0);
        }
        __syncthreads();
    }
    #pragma unroll
    for (int fm = 0; fm < 4; ++fm) {
        #pragma unroll
        for (int r = 0; r < 4; ++r) {
            int row = m0 + wm * 64 + fm * 16 + (lane >> 4) * 4 + r;
            int b_ = row >> 11, t = row & 2047;
            size_t base = ((size_t)b_ * TP + t + 2) * Cc;
            #pragma unroll
            for (int fn = 0; fn < 4; ++fn) {
                int col = n0 + wn * 64 + fn * 16 + (lane & 15);
                Gp[base + col] = f2bf(acc[fm][fn][r]);
            }
        }
    }
}

// ---------------- K3: conv1d(K=5) GEMM + relu + max_f -> att_v ----------
// BM=256, BN=256, 8 waves 4M x 2N (wave tile 64x128, acc[4][8]).
// T4 counted-vmcnt skeleton. FIX vs rounds 7/9: channel loop is 16 chunks
// (ct<15 + tail ct=15, s=0..79) — the C=1024 reduction is independent of BM;
// rounds 7/9 only summed 8 chunks = 512 channels (absmax 680, deterministic).
// A: 40 uniform segs/ct (5/thread; segs 33..39 pad reads within ws), dbuf.
// B: per (ct,k), dbuf. Entry waits per ct: 4,9,9,4,4; tail: 4,4,4,4,0.
__global__ __launch_bounds__(512) void k_conv(const u16* __restrict__ Gp,
                                              const u16* __restrict__ Wt,
                                              const float* __restrict__ bias,
                                              float* __restrict__ att) {
    __shared__ alignas(16) u16 As[2][40 * 512];   // 81,920 B
    __shared__ alignas(16) u16 Bs[2][256 * 64];   // 65,536 B
    __shared__ float red[2][256];                 //  2,048 B (149,504 total)
    int mt = blockIdx.x;                 // 512 blocks
    int b_ = mt >> 3;                    // 8 tiles per batch
    int t0 = (mt & 7) * 256;
    int tid = threadIdx.x, lane = tid & 63, wid = tid >> 6;
    int wm = wid >> 1, wn = wid & 1;     // 4M x 2N
    int srow = lane >> 3, scol = swz_scol(lane);
    f32x4 acc[4][8] = {};
    const size_t gbase = ((size_t)b_ * TP + t0) * Cc;

    auto stage_B = [&](int s2) {          // 4 gl_lds/thread
        int ct2 = s2 / 5, k2 = s2 % 5, buf = s2 & 1;
        #pragma unroll
        for (int i = 0; i < 4; ++i) {
            int seg = wid * 4 + i;
            gl_lds16(Wt + ((size_t)k2 * Ff + seg * 8 + srow) * Cc + ct2 * 64 + scol,
                     &Bs[buf][seg * 512]);
        }
    };
    auto stage_A = [&](int ct2) {         // 5 gl_lds/thread (uniform, padded)
        int buf = ct2 & 1;
        #pragma unroll
        for (int i = 0; i < 5; ++i) {
            int seg = wid * 5 + i;        // 0..39; segs 33..39 load garbage
            gl_lds16(Gp + gbase + (size_t)(seg * 8 + srow) * Cc + ct2 * 64 + scol,
                     &As[buf][seg * 512]);
        }
    };
    auto compute = [&](int cb, int ca, int k) {
        #pragma unroll
        for (int kk = 0; kk < 2; ++kk) {
            int rsel = lane & 15, ksel = kk * 32 + (lane >> 4) * 8;
            s16x8 a[4], b[8];
            #pragma unroll
            for (int f = 0; f < 4; ++f) {
                int row = k + wm * 64 + f * 16 + rsel;
                a[f] = *(const s16x8*)&As[ca][row * 64 + swz_rd(row, ksel)];
            }
            #pragma unroll
            for (int f = 0; f < 8; ++f) {
                int row = wn * 128 + f * 16 + rsel;
                b[f] = *(const s16x8*)&Bs[cb][row * 64 + swz_rd(row, ksel)];
            }
            #pragma unroll
            for (int fm = 0; fm < 4; ++fm)
                #pragma unroll
                for (int fn = 0; fn < 8; ++fn)
                    acc[fm][fn] = __builtin_amdgcn_mfma_f32_16x16x32_bf16(
                        a[fm], b[fn], acc[fm][fn], 0, 0, 0);
        }
    };

    // prologue: A(0)[5] + B(0)[4] + B(1)[4] = 13 in flight
    stage_A(0); stage_B(0); stage_B(1);

    for (int ct = 0; ct < 15; ++ct) {
        int s = ct * 5, ca = ct & 1;
        // k=0
        VMW(4); SCHEDB(); BARM();
        compute(s & 1, ca, 0);
        BARM();
        stage_B(s + 2); stage_A(ct + 1);
        // k=1
        VMW(9); SCHEDB(); BARM();
        compute((s + 1) & 1, ca, 1);
        BARM();
        stage_B(s + 3);
        // k=2
        VMW(9); SCHEDB(); BARM();
        compute((s + 2) & 1, ca, 2);
        BARM();
        stage_B(s + 4);
        // k=3
        VMW(4); SCHEDB(); BARM();
        compute((s + 3) & 1, ca, 3);
        BARM();
        stage_B(s + 5);
        // k=4
        VMW(4); SCHEDB(); BARM();
        compute((s + 4) & 1, ca, 4);
        BARM();
        stage_B(s + 6);
    }
    // ct = 15 (s = 75..79): no A issue at k==0, drain tail
    VMW(4); SCHEDB(); BARM(); compute(1, 1, 0); BARM(); stage_B(77);
    VMW(4); SCHEDB(); BARM(); compute(0, 1, 1); BARM(); stage_B(78);
    VMW(4); SCHEDB(); BARM(); compute(1, 1, 2); BARM(); stage_B(79);
    VMW(4); SCHEDB(); BARM(); compute(0, 1, 3); BARM();
    VMW(0); SCHEDB(); BARM(); compute(1, 1, 4); BARM();

    // epilogue: relu(acc+bias), max over all 256 filters -> att_v
    float bv[8];
    #pragma unroll
    for (int fn = 0; fn < 8; ++fn)
        bv[fn] = bias[wn * 128 + fn * 16 + (lane & 15)];
    #pragma unroll
    for (int fm = 0; fm < 4; ++fm) {
        #pragma unroll
        for (int r = 0; r < 4; ++r) {
            float v = 0.f;
            #pragma unroll
            for (int fn = 0; fn < 8; ++fn)
                v = fmaxf(v, fmaxf(acc[fm][fn][r] + bv[fn], 0.f));
            #pragma unroll
            for (int m = 1; m <= 8; m <<= 1) v = fmaxf(v, __shfl_xor(v, m));
            if ((lane & 15) == 0)
                red[wn][wm * 64 + fm * 16 + (lane >> 4) * 4 + r] = v;
        }
    }
    __syncthreads();
    if (tid < 256)
        att[(size_t)mt * 256 + tid] = fmaxf(red[0][tid], red[1][tid]);
}

// ---------------- K4: H partials (bf16 S) ----------------
__global__ __launch_bounds__(256) void k_henc_bf(const u16* __restrict__ Sb,
                                                 const float* __restrict__ att,
                                                 float* __restrict__ part) {
    int b_ = blockIdx.x, tc = blockIdx.y;
    int tid = threadIdx.x;
    int d = tid * 4;
    const u16* Sp = Sb + ((size_t)b_ * Tt + (size_t)tc * 256) * Dd + d;
    const float* ap = att + (size_t)b_ * Tt + (size_t)tc * 256;
    f32x4 acc = {};
    for (int t = 0; t < 256; ++t) {
        float a = ap[t];
        u16x4 s = *(const u16x4*)(Sp + (size_t)t * Dd);
        acc.x += bf2f(s.x) * a;
        acc.y += bf2f(s.y) * a;
        acc.z += bf2f(s.z) * a;
        acc.w += bf2f(s.w) * a;
    }
    *(f32x4*)(part + ((size_t)tc * Bb + b_) * Dd + d) = acc;
}

// ---------------- K4-fallback: f32 S ----------------
__global__ __launch_bounds__(256) void k_henc_f32(const float* __restrict__ S,
                                                  const float* __restrict__ att,
                                                  float* __restrict__ part) {
    int b_ = blockIdx.x, tc = blockIdx.y;
    int tid = threadIdx.x;
    int d = tid * 4;
    const float* Sp = S + ((size_t)b_ * Tt + (size_t)tc * 256) * Dd + d;
    const float* ap = att + (size_t)b_ * Tt + (size_t)tc * 256;
    f32x4 acc = {};
    for (int t = 0; t < 256; ++t) {
        float a = ap[t];
        f32x4 s = *(const f32x4*)(Sp + (size_t)t * Dd);
        acc += s * a;
    }
    *(f32x4*)(part + ((size_t)tc * Bb + b_) * Dd + d) = acc;
}

// ---------------- K5: reduce 8 partials -> d_out ----------------
__global__ __launch_bounds__(256) void k_hred(const float* __restrict__ part,
                                              float* __restrict__ out) {
    int i = blockIdx.x * 256 + threadIdx.x;
    float s = 0.f;
    #pragma unroll
    for (int p = 0; p < 8; ++p) s += part[(size_t)p * (Bb * Dd) + i];
    out[i] = s;
}

extern "C" void kernel_launch(void* const* d_in, const int* in_sizes, int n_in,
                              void* d_out, int out_size, void* d_ws, size_t ws_size,
                              hipStream_t stream) {
    const float* S  = (const float*)d_in[0];
    const float* L  = (const float*)d_in[1];
    const float* W  = (const float*)d_in[2];
    const float* cb = (const float*)d_in[3];
    float* out = (float*)d_out;
    char* ws = (char*)d_ws;

    const size_t GP_B   = (size_t)Bb * TP * Cc * 2;   // 268,959,744
    const size_t LN_B   = (size_t)Cc * Dd * 2;        //   2,097,152
    const size_t WT_B   = (size_t)5 * Ff * Cc * 2;    //   2,621,440
    const size_t ATT_B  = (size_t)M1 * 4;             //     524,288
    const size_t PART_B = (size_t)8 * Bb * Dd * 4;    //   2,097,152
    const size_t SB_B   = (size_t)M1 * Dd * 2;        // 268,435,456
    u16*   Gp   = (u16*)(ws);
    u16*   Ln   = (u16*)(ws + GP_B);
    u16*   Wt   = (u16*)(ws + GP_B + LN_B);
    float* att  = (float*)(ws + GP_B + LN_B + WT_B);
    float* part = (float*)(ws + GP_B + LN_B + WT_B + ATT_B);
    u16*   Sb   = (u16*)(ws + GP_B + LN_B + WT_B + ATT_B + PART_B);
    const bool use_bf = ws_size >= GP_B + LN_B + WT_B + ATT_B + PART_B + SB_B;

    k_label_norm<<<Cc, 256, 0, stream>>>(L, Ln);
    k_wt<<<dim3(5, Cc / 64, Ff / 64), 256, 0, stream>>>(W, Wt);
    k_zpad<<<Bb, 256, 0, stream>>>(Gp);
    if (use_bf) {
        k_s2bf<<<2048, 256, 0, stream>>>(S, Sb);
        k_gemm1_8ph<<<(M1 / 256) * (Cc / 256), 512, 0, stream>>>(Sb, Ln, Gp);
    } else {
        k_gemm1_f32<<<(M1 / 128) * (Cc / 128), 256, 0, stream>>>(S, Ln, Gp);
    }
    k_conv<<<M1 / 256, 512, 0, stream>>>(Gp, Wt, cb, att);
    if (use_bf) k_henc_bf<<<dim3(Bb, 8), 256, 0, stream>>>(Sb, att, part);
    else        k_henc_f32<<<dim3(Bb, 8), 256, 0, stream>>>(S, att, part);
    k_hred<<<(Bb * Dd) / 256, 256, 0, stream>>>(part, out);
}

// Round 11
// 819.654 us; speedup vs baseline: 1.0954x; 1.0115x over previous
//
#include <hip/hip_runtime.h>

typedef unsigned short u16;
typedef __attribute__((ext_vector_type(4))) float f32x4;
typedef __attribute__((ext_vector_type(8))) short s16x8;
typedef __attribute__((ext_vector_type(4))) unsigned short u16x4;

#define DEV __device__ __forceinline__
#define VMW(N) asm volatile("s_waitcnt vmcnt(" #N ")" ::: "memory")
#define BARM() asm volatile("s_barrier" ::: "memory")
#define SCHEDB() __builtin_amdgcn_sched_barrier(0)

// Problem constants
constexpr int Bb = 64, Tt = 2048, Dd = 1024, Cc = 1024, Ff = 256;
constexpr int TP = Tt + 4;            // padded time (2 halo rows each side)
constexpr int M1 = Bb * Tt;           // 131072

DEV u16 f2bf(float f) {               // RNE f32 -> bf16
    union { float f; unsigned u; } v; v.f = f;
    unsigned r = v.u + 0x7fffu + ((v.u >> 16) & 1u);
    return (u16)(r >> 16);
}
DEV float bf2f(u16 h) {
    union { unsigned u; float f; } v; v.u = ((unsigned)h) << 16; return v.f;
}

// async global->LDS, 16B per lane. lds dest must be wave-uniform base;
// HW writes lane l at base + l*16.
DEV void gl_lds16(const u16* g, u16* l) {
    __builtin_amdgcn_global_load_lds(
        (const __attribute__((address_space(1))) unsigned*)(const void*)g,
        (__attribute__((address_space(3))) unsigned*)(void*)l,
        16, 0, 0);
}

// T2 swizzle helpers (16B-slot XOR within 128B row):
DEV int swz_scol(int lane) { return (((lane & 7) ^ ((lane >> 3) & 7)) << 3); }
DEV int swz_rd(int row, int e) { return e ^ ((row & 7) << 3); }

// ---------------- K-1: S f32 -> bf16 ----------------
__global__ __launch_bounds__(256) void k_s2bf(const float* __restrict__ S,
                                              u16* __restrict__ Sb) {
    size_t i = ((size_t)blockIdx.x * 256 + threadIdx.x) * 8;
    const size_t stride = (size_t)gridDim.x * 256 * 8;
    const size_t n = (size_t)M1 * Dd;
    for (; i < n; i += stride) {
        f32x4 a = *(const f32x4*)(S + i);
        f32x4 b = *(const f32x4*)(S + i + 4);
        s16x8 r;
        r[0] = (short)f2bf(a.x); r[1] = (short)f2bf(a.y);
        r[2] = (short)f2bf(a.z); r[3] = (short)f2bf(a.w);
        r[4] = (short)f2bf(b.x); r[5] = (short)f2bf(b.y);
        r[6] = (short)f2bf(b.z); r[7] = (short)f2bf(b.w);
        *(s16x8*)(Sb + i) = r;
    }
}

// ---------------- K0: l2-normalize label rows, cast bf16 ----------------
__global__ __launch_bounds__(256) void k_label_norm(const float* __restrict__ L,
                                                    u16* __restrict__ Ln) {
    int c = blockIdx.x;
    int t = threadIdx.x;
    const float* row = L + (size_t)c * Dd;
    float s = 0.f;
    for (int d = t; d < Dd; d += 256) { float v = row[d]; s += v * v; }
    for (int o = 32; o; o >>= 1) s += __shfl_down(s, o);
    __shared__ float red[4];
    if ((t & 63) == 0) red[t >> 6] = s;
    __syncthreads();
    float tot = red[0] + red[1] + red[2] + red[3];
    float r = rsqrtf(fmaxf(tot, 1e-12f));
    for (int d = t; d < Dd; d += 256) Ln[(size_t)c * Dd + d] = f2bf(row[d] * r);
}

// ---------------- K0b: transpose conv_w (K,C,F) f32 -> Wt (K,F,C) bf16 --
__global__ __launch_bounds__(256) void k_wt(const float* __restrict__ W,
                                            u16* __restrict__ Wt) {
    __shared__ float tile[64][65];
    int k = blockIdx.x; int c0 = blockIdx.y * 64; int f0 = blockIdx.z * 64;
    int tid = threadIdx.x;
    const float* Wk = W + (size_t)k * Cc * Ff;
    #pragma unroll
    for (int i = 0; i < 16; ++i) {
        int q = tid + i * 256;
        int ci = q >> 6, fj = q & 63;
        tile[ci][fj] = Wk[(size_t)(c0 + ci) * Ff + f0 + fj];
    }
    __syncthreads();
    #pragma unroll
    for (int i = 0; i < 16; ++i) {
        int q = tid + i * 256;
        int fi = q >> 6, cj = q & 63;
        Wt[((size_t)k * Ff + f0 + fi) * Cc + c0 + cj] = f2bf(tile[cj][fi]);
    }
}

// ---------------- K1: zero the halo rows of padded G ----------------
__global__ __launch_bounds__(256) void k_zpad(u16* __restrict__ Gp) {
    int b_ = blockIdx.x, tid = threadIdx.x;
    size_t base = (size_t)b_ * TP * Cc;
    for (int i = tid; i < 2 * Cc; i += 256) {
        Gp[base + i] = 0;
        Gp[base + (size_t)(TP - 2) * Cc + i] = 0;
    }
}

// ---------------- K2: G = Sb @ Ln^T  (256x256, conv-style T4 skeleton) --
// BM=BN=256, BK=64, 8 waves (2M x 4N, wave tile 128x64 contiguous).
// Per kt: VMW(counted) -> barrier -> {24 ds_read + 64 MFMA} -> barrier ->
// stage(kt+2) [8 gl_lds/thread]. 2 barriers/kt (was ~9 in the 4-phase
// version -> barrier-dominated at 1:7 barrier:MFMA; conv's 1:32 ratio
// hits 48% peak). Ledger: prologue stages kt=0,1 (16 in flight); entry
// VMW(8) kt=0..14 (oldest 8 = this kt's stage), VMW(0) at kt=15.
// stage(kt+2) reuses buffer drained by compute(kt) (post-barrier).
__global__ __launch_bounds__(512) void k_gemm1_t4(const u16* __restrict__ Sb,
                                                  const u16* __restrict__ Ln,
                                                  u16* __restrict__ Gp) {
    __shared__ alignas(16) u16 As[2][256 * 64];   // 64 KiB
    __shared__ alignas(16) u16 Bs[2][256 * 64];   // 64 KiB
    int bid = blockIdx.x;
    int xcd = bid & 7, idx = bid >> 3;
    int mt = xcd * 64 + (idx >> 2);      // 512 mt
    int nt = idx & 3;                    // 4 nt
    const int m0 = mt * 256, n0 = nt * 256;
    int tid = threadIdx.x, lane = tid & 63, wid = tid >> 6;
    int wm = wid >> 2, wn = wid & 3;     // 2M x 4N
    int srow = lane >> 3, scol = swz_scol(lane);
    const int rsel = lane & 15;
    f32x4 acc[8][4] = {};

    auto stageA = [&](int kt, int buf) {   // 4 gl_lds/thread
        #pragma unroll
        for (int i = 0; i < 4; ++i) {
            int seg = wid * 4 + i;             // 0..31
            gl_lds16(Sb + (size_t)(m0 + seg * 8 + srow) * Dd + kt * 64 + scol,
                     &As[buf][seg * 512]);
        }
    };
    auto stageB = [&](int kt, int buf) {   // 4 gl_lds/thread
        #pragma unroll
        for (int i = 0; i < 4; ++i) {
            int seg = wid * 4 + i;
            gl_lds16(Ln + (size_t)(n0 + seg * 8 + srow) * Dd + kt * 64 + scol,
                     &Bs[buf][seg * 512]);
        }
    };
    auto compute = [&](int buf) {
        #pragma unroll
        for (int kk = 0; kk < 2; ++kk) {
            int ksel = kk * 32 + (lane >> 4) * 8;
            s16x8 a[8], b[4];
            #pragma unroll
            for (int f = 0; f < 8; ++f) {
                int row = wm * 128 + f * 16 + rsel;
                a[f] = *(const s16x8*)&As[buf][row * 64 + swz_rd(row, ksel)];
            }
            #pragma unroll
            for (int f = 0; f < 4; ++f) {
                int row = wn * 64 + f * 16 + rsel;
                b[f] = *(const s16x8*)&Bs[buf][row * 64 + swz_rd(row, ksel)];
            }
            __builtin_amdgcn_s_setprio(1);
            #pragma unroll
            for (int fm = 0; fm < 8; ++fm)
                #pragma unroll
                for (int fn = 0; fn < 4; ++fn)
                    acc[fm][fn] = __builtin_amdgcn_mfma_f32_16x16x32_bf16(
                        a[fm], b[fn], acc[fm][fn], 0, 0, 0);
            __builtin_amdgcn_s_setprio(0);
        }
    };

    // prologue: stage kt=0 (buf0), kt=1 (buf1) -> 16 loads/thread in flight
    stageA(0, 0); stageB(0, 0);
    stageA(1, 1); stageB(1, 1);

    for (int kt = 0; kt < 16; ++kt) {
        if (kt < 15) { VMW(8); } else { VMW(0); }
        SCHEDB(); BARM();
        compute(kt & 1);
        BARM();
        if (kt < 14) { stageA(kt + 2, kt & 1); stageB(kt + 2, kt & 1); }
    }

    // epilogue: wave rows [wm*128, +128), cols [wn*64, +64)
    #pragma unroll
    for (int m = 0; m < 8; ++m) {
        #pragma unroll
        for (int r = 0; r < 4; ++r) {
            int row = m0 + wm * 128 + m * 16 + (lane >> 4) * 4 + r;
            int b_ = row >> 11, t = row & 2047;
            size_t base = ((size_t)b_ * TP + t + 2) * Cc;
            #pragma unroll
            for (int n = 0; n < 4; ++n) {
                int col = n0 + wn * 64 + n * 16 + rsel;
                Gp[base + col] = f2bf(acc[m][n][r]);
            }
        }
    }
}

// ---------------- K2-fallback: f32 A path (linear LDS, consistent) ------
__global__ __launch_bounds__(256) void k_gemm1_f32(const float* __restrict__ S,
                                                   const u16* __restrict__ Ln,
                                                   u16* __restrict__ Gp) {
    __shared__ alignas(16) u16 As[128 * 64];
    __shared__ alignas(16) u16 Bs[128 * 64];
    int bid = blockIdx.x;
    int xcd = bid & 7, idx = bid >> 3;
    int mt = xcd * 128 + (idx >> 3);
    int nt = idx & 7;
    const int m0 = mt * 128, n0 = nt * 128;
    int tid = threadIdx.x;
    int lane = tid & 63, wid = tid >> 6;
    int wm = wid >> 1, wn = wid & 1;
    f32x4 acc[4][4] = {};

    for (int kt = 0; kt < 16; ++kt) {
        int k0 = kt * 64;
        #pragma unroll
        for (int i = 0; i < 8; ++i) {
            int q = tid + i * 256;
            int row = q >> 4, c4 = (q & 15) * 4;
            f32x4 v = *(const f32x4*)(S + (size_t)(m0 + row) * Dd + k0 + c4);
            u16* p = &As[row * 64 + c4];
            p[0] = f2bf(v.x); p[1] = f2bf(v.y); p[2] = f2bf(v.z); p[3] = f2bf(v.w);
        }
        #pragma unroll
        for (int i = 0; i < 4; ++i) {
            int q = tid + i * 256;
            int row = q >> 3, c8 = (q & 7) * 8;
            *(s16x8*)&Bs[row * 64 + c8] =
                *(const s16x8*)(Ln + (size_t)(n0 + row) * Dd + k0 + c8);
        }
        __syncthreads();
        #pragma unroll
        for (int kk = 0; kk < 2; ++kk) {
            int rsel = lane & 15, ksel = kk * 32 + (lane >> 4) * 8;
            s16x8 a[4], b[4];
            #pragma unroll
            for (int f = 0; f < 4; ++f)
                a[f] = *(const s16x8*)&As[(wm * 64 + f * 16 + rsel) * 64 + ksel];
            #pragma unroll
            for (int f = 0; f < 4; ++f)
                b[f] = *(const s16x8*)&Bs[(wn * 64 + f * 16 + rsel) * 64 + ksel];
            #pragma unroll
            for (int fm = 0; fm < 4; ++fm)
                #pragma unroll
                for (int fn = 0; fn < 4; ++fn)
                    acc[fm][fn] = __builtin_amdgcn_mfma_f32_16x16x32_bf16(
                        a[fm], b[fn], acc[fm][fn], 0, 0, 0);
        }
        __syncthreads();
    }
    #pragma unroll
    for (int fm = 0; fm < 4; ++fm) {
        #pragma unroll
        for (int r = 0; r < 4; ++r) {
            int row = m0 + wm * 64 + fm * 16 + (lane >> 4) * 4 + r;
            int b_ = row >> 11, t = row & 2047;
            size_t base = ((size_t)b_ * TP + t + 2) * Cc;
            #pragma unroll
            for (int fn = 0; fn < 4; ++fn) {
                int col = n0 + wn * 64 + fn * 16 + (lane & 15);
                Gp[base + col] = f2bf(acc[fm][fn][r]);
            }
        }
    }
}

// ---------------- K3: conv1d(K=5) GEMM + relu + max_f (ROUND-10 EXACT) --
// BM=256, BN=256, 8 waves 4M x 2N (wave tile 64x128, acc[4][8]).
// 16 channel chunks (ct<15 + tail ct=15). Entry waits 4,9,9,4,4; tail
// 4,4,4,4,0. Passed @ absmax 8.0, ~285us, ~1210 TF.
__global__ __launch_bounds__(512) void k_conv(const u16* __restrict__ Gp,
                                              const u16* __restrict__ Wt,
                                              const float* __restrict__ bias,
                                              float* __restrict__ att) {
    __shared__ alignas(16) u16 As[2][40 * 512];   // 81,920 B
    __shared__ alignas(16) u16 Bs[2][256 * 64];   // 65,536 B
    __shared__ float red[2][256];                 //  2,048 B (149,504 total)
    int mt = blockIdx.x;                 // 512 blocks
    int b_ = mt >> 3;                    // 8 tiles per batch
    int t0 = (mt & 7) * 256;
    int tid = threadIdx.x, lane = tid & 63, wid = tid >> 6;
    int wm = wid >> 1, wn = wid & 1;     // 4M x 2N
    int srow = lane >> 3, scol = swz_scol(lane);
    f32x4 acc[4][8] = {};
    const size_t gbase = ((size_t)b_ * TP + t0) * Cc;

    auto stage_B = [&](int s2) {          // 4 gl_lds/thread
        int ct2 = s2 / 5, k2 = s2 % 5, buf = s2 & 1;
        #pragma unroll
        for (int i = 0; i < 4; ++i) {
            int seg = wid * 4 + i;
            gl_lds16(Wt + ((size_t)k2 * Ff + seg * 8 + srow) * Cc + ct2 * 64 + scol,
                     &Bs[buf][seg * 512]);
        }
    };
    auto stage_A = [&](int ct2) {         // 5 gl_lds/thread (uniform, padded)
        int buf = ct2 & 1;
        #pragma unroll
        for (int i = 0; i < 5; ++i) {
            int seg = wid * 5 + i;        // 0..39; segs 33..39 load garbage
            gl_lds16(Gp + gbase + (size_t)(seg * 8 + srow) * Cc + ct2 * 64 + scol,
                     &As[buf][seg * 512]);
        }
    };
    auto compute = [&](int cb, int ca, int k) {
        #pragma unroll
        for (int kk = 0; kk < 2; ++kk) {
            int rsel = lane & 15, ksel = kk * 32 + (lane >> 4) * 8;
            s16x8 a[4], b[8];
            #pragma unroll
            for (int f = 0; f < 4; ++f) {
                int row = k + wm * 64 + f * 16 + rsel;
                a[f] = *(const s16x8*)&As[ca][row * 64 + swz_rd(row, ksel)];
            }
            #pragma unroll
            for (int f = 0; f < 8; ++f) {
                int row = wn * 128 + f * 16 + rsel;
                b[f] = *(const s16x8*)&Bs[cb][row * 64 + swz_rd(row, ksel)];
            }
            #pragma unroll
            for (int fm = 0; fm < 4; ++fm)
                #pragma unroll
                for (int fn = 0; fn < 8; ++fn)
                    acc[fm][fn] = __builtin_amdgcn_mfma_f32_16x16x32_bf16(
                        a[fm], b[fn], acc[fm][fn], 0, 0, 0);
        }
    };

    // prologue: A(0)[5] + B(0)[4] + B(1)[4] = 13 in flight
    stage_A(0); stage_B(0); stage_B(1);

    for (int ct = 0; ct < 15; ++ct) {
        int s = ct * 5, ca = ct & 1;
        // k=0
        VMW(4); SCHEDB(); BARM();
        compute(s & 1, ca, 0);
        BARM();
        stage_B(s + 2); stage_A(ct + 1);
        // k=1
        VMW(9); SCHEDB(); BARM();
        compute((s + 1) & 1, ca, 1);
        BARM();
        stage_B(s + 3);
        // k=2
        VMW(9); SCHEDB(); BARM();
        compute((s + 2) & 1, ca, 2);
        BARM();
        stage_B(s + 4);
        // k=3
        VMW(4); SCHEDB(); BARM();
        compute((s + 3) & 1, ca, 3);
        BARM();
        stage_B(s + 5);
        // k=4
        VMW(4); SCHEDB(); BARM();
        compute((s + 4) & 1, ca, 4);
        BARM();
        stage_B(s + 6);
    }
    // ct = 15 (s = 75..79): no A issue at k==0, drain tail
    VMW(4); SCHEDB(); BARM(); compute(1, 1, 0); BARM(); stage_B(77);
    VMW(4); SCHEDB(); BARM(); compute(0, 1, 1); BARM(); stage_B(78);
    VMW(4); SCHEDB(); BARM(); compute(1, 1, 2); BARM(); stage_B(79);
    VMW(4); SCHEDB(); BARM(); compute(0, 1, 3); BARM();
    VMW(0); SCHEDB(); BARM(); compute(1, 1, 4); BARM();

    // epilogue: relu(acc+bias), max over all 256 filters -> att_v
    float bv[8];
    #pragma unroll
    for (int fn = 0; fn < 8; ++fn)
        bv[fn] = bias[wn * 128 + fn * 16 + (lane & 15)];
    #pragma unroll
    for (int fm = 0; fm < 4; ++fm) {
        #pragma unroll
        for (int r = 0; r < 4; ++r) {
            float v = 0.f;
            #pragma unroll
            for (int fn = 0; fn < 8; ++fn)
                v = fmaxf(v, fmaxf(acc[fm][fn][r] + bv[fn], 0.f));
            #pragma unroll
            for (int m = 1; m <= 8; m <<= 1) v = fmaxf(v, __shfl_xor(v, m));
            if ((lane & 15) == 0)
                red[wn][wm * 64 + fm * 16 + (lane >> 4) * 4 + r] = v;
        }
    }
    __syncthreads();
    if (tid < 256)
        att[(size_t)mt * 256 + tid] = fmaxf(red[0][tid], red[1][tid]);
}

// ---------------- K4: H partials (bf16 S) ----------------
__global__ __launch_bounds__(256) void k_henc_bf(const u16* __restrict__ Sb,
                                                 const float* __restrict__ att,
                                                 float* __restrict__ part) {
    int b_ = blockIdx.x, tc = blockIdx.y;
    int tid = threadIdx.x;
    int d = tid * 4;
    const u16* Sp = Sb + ((size_t)b_ * Tt + (size_t)tc * 256) * Dd + d;
    const float* ap = att + (size_t)b_ * Tt + (size_t)tc * 256;
    f32x4 acc = {};
    for (int t = 0; t < 256; ++t) {
        float a = ap[t];
        u16x4 s = *(const u16x4*)(Sp + (size_t)t * Dd);
        acc.x += bf2f(s.x) * a;
        acc.y += bf2f(s.y) * a;
        acc.z += bf2f(s.z) * a;
        acc.w += bf2f(s.w) * a;
    }
    *(f32x4*)(part + ((size_t)tc * Bb + b_) * Dd + d) = acc;
}

// ---------------- K4-fallback: f32 S ----------------
__global__ __launch_bounds__(256) void k_henc_f32(const float* __restrict__ S,
                                                  const float* __restrict__ att,
                                                  float* __restrict__ part) {
    int b_ = blockIdx.x, tc = blockIdx.y;
    int tid = threadIdx.x;
    int d = tid * 4;
    const float* Sp = S + ((size_t)b_ * Tt + (size_t)tc * 256) * Dd + d;
    const float* ap = att + (size_t)b_ * Tt + (size_t)tc * 256;
    f32x4 acc = {};
    for (int t = 0; t < 256; ++t) {
        float a = ap[t];
        f32x4 s = *(const f32x4*)(Sp + (size_t)t * Dd);
        acc += s * a;
    }
    *(f32x4*)(part + ((size_t)tc * Bb + b_) * Dd + d) = acc;
}

// ---------------- K5: reduce 8 partials -> d_out ----------------
__global__ __launch_bounds__(256) void k_hred(const float* __restrict__ part,
                                              float* __restrict__ out) {
    int i = blockIdx.x * 256 + threadIdx.x;
    float s = 0.f;
    #pragma unroll
    for (int p = 0; p < 8; ++p) s += part[(size_t)p * (Bb * Dd) + i];
    out[i] = s;
}

extern "C" void kernel_launch(void* const* d_in, const int* in_sizes, int n_in,
                              void* d_out, int out_size, void* d_ws, size_t ws_size,
                              hipStream_t stream) {
    const float* S  = (const float*)d_in[0];
    const float* L  = (const float*)d_in[1];
    const float* W  = (const float*)d_in[2];
    const float* cb = (const float*)d_in[3];
    float* out = (float*)d_out;
    char* ws = (char*)d_ws;

    const size_t GP_B   = (size_t)Bb * TP * Cc * 2;   // 268,959,744
    const size_t LN_B   = (size_t)Cc * Dd * 2;        //   2,097,152
    const size_t WT_B   = (size_t)5 * Ff * Cc * 2;    //   2,621,440
    const size_t ATT_B  = (size_t)M1 * 4;             //     524,288
    const size_t PART_B = (size_t)8 * Bb * Dd * 4;    //   2,097,152
    const size_t SB_B   = (size_t)M1 * Dd * 2;        // 268,435,456
    u16*   Gp   = (u16*)(ws);
    u16*   Ln   = (u16*)(ws + GP_B);
    u16*   Wt   = (u16*)(ws + GP_B + LN_B);
    float* att  = (float*)(ws + GP_B + LN_B + WT_B);
    float* part = (float*)(ws + GP_B + LN_B + WT_B + ATT_B);
    u16*   Sb   = (u16*)(ws + GP_B + LN_B + WT_B + ATT_B + PART_B);
    const bool use_bf = ws_size >= GP_B + LN_B + WT_B + ATT_B + PART_B + SB_B;

    k_label_norm<<<Cc, 256, 0, stream>>>(L, Ln);
    k_wt<<<dim3(5, Cc / 64, Ff / 64), 256, 0, stream>>>(W, Wt);
    k_zpad<<<Bb, 256, 0, stream>>>(Gp);
    if (use_bf) {
        k_s2bf<<<2048, 256, 0, stream>>>(S, Sb);
        k_gemm1_t4<<<(M1 / 256) * (Cc / 256), 512, 0, stream>>>(Sb, Ln, Gp);
    } else {
        k_gemm1_f32<<<(M1 / 128) * (Cc / 128), 256, 0, stream>>>(S, Ln, Gp);
    }
    k_conv<<<M1 / 256, 512, 0, stream>>>(Gp, Wt, cb, att);
    if (use_bf) k_henc_bf<<<dim3(Bb, 8), 256, 0, stream>>>(Sb, att, part);
    else        k_henc_f32<<<dim3(Bb, 8), 256, 0, stream>>>(S, att, part);
    k_hred<<<(Bb * Dd) / 256, 256, 0, stream>>>(part, out);
}